// Round 4
// baseline (132.569 us; speedup 1.0000x reference)
//
#include <hip/hip_runtime.h>

constexpr int B    = 4;
constexpr int CIN  = 192;
constexpr int COUT = 192;
constexpr int NN   = 16384;
constexpr int KK   = 16;
constexpr int NG   = 4;    // groups
constexpr int GIN  = 48;   // fan_in per group
constexpr int GOUT = 48;   // out channels per group

__device__ __forceinline__ float4 f4add(float4 a, float4 b) {
    return make_float4(a.x + b.x, a.y + b.y, a.z + b.z, a.w + b.w);
}

// ---------------------------------------------------------------------------
// Kernel 1 (gemm_y): y = W x, grouped 48x48, computed BEFORE the gather.
// GIN is linear pre-ReLU: ReLU(W((1+e)x_i + sum x_j) + b)
//                       = ReLU((1+e)(Wx)_i + sum (Wx)_j + b).
// Reads x (B,C,N) directly (replaces the old transpose kernel), writes y in
// (b, g, n, 48) node-major layout — each node's group-slice is 192 B
// contiguous, exactly what the gather wants.  2048 blocks of 32 nodes.
// ---------------------------------------------------------------------------
constexpr int NT1  = 32;
constexpr int TPB1 = 192;

__global__ __launch_bounds__(TPB1, 4) void gemm_y(const float* __restrict__ x,
                                                  const float* __restrict__ w,
                                                  float* __restrict__ y) {
    __shared__ __align__(16) float x_lds[CIN * NT1];   // [c][i], 24 KB
    __shared__ __align__(16) float yo[NT1 * GOUT];     // [i][co], 6 KB

    const int tid = threadIdx.x;
    const int blk = blockIdx.x;
    const int b   = blk & 3;            // %8 XCD round-robin -> one batch/XCD-pair
    const int n0  = (blk >> 2) * NT1;

    const float* xb = x + (size_t)b * CIN * NN;
    // stage x tile: rows c, 8 float4 per row (coalesced), LDS writes linear
    for (int t = tid; t < CIN * (NT1 / 4); t += TPB1) {
        const int c = t >> 3, i4 = t & 7;
        ((float4*)(x_lds + c * NT1))[i4] =
            *(const float4*)(xb + (size_t)c * NN + n0 + 4 * i4);
    }
    __syncthreads();

    const int co = tid % GOUT;  // 0..47
    const int q  = tid / GOUT;  // 0..3 -> nodes q*8..q*8+7

    for (int g = 0; g < NG; ++g) {
        float4 wv[12];
        const float* wr = w + (size_t)(g * GOUT + co) * GIN;
#pragma unroll
        for (int ii = 0; ii < 12; ++ii) wv[ii] = ((const float4*)wr)[ii];

        float acc[8] = {0.f, 0.f, 0.f, 0.f, 0.f, 0.f, 0.f, 0.f};
#pragma unroll
        for (int ci4 = 0; ci4 < 12; ++ci4) {
            const float* xr0 = x_lds + (g * GIN + 4 * ci4) * NT1 + q * 8;
#pragma unroll
            for (int r = 0; r < 4; ++r) {
                // broadcast reads: all lanes with same q read same address
                const float4 xa = ((const float4*)(xr0 + r * NT1))[0];
                const float4 xc = ((const float4*)(xr0 + r * NT1))[1];
                const float ws = (r == 0) ? wv[ci4].x : (r == 1) ? wv[ci4].y
                               : (r == 2) ? wv[ci4].z : wv[ci4].w;
                acc[0] = fmaf(ws, xa.x, acc[0]);
                acc[1] = fmaf(ws, xa.y, acc[1]);
                acc[2] = fmaf(ws, xa.z, acc[2]);
                acc[3] = fmaf(ws, xa.w, acc[3]);
                acc[4] = fmaf(ws, xc.x, acc[4]);
                acc[5] = fmaf(ws, xc.y, acc[5]);
                acc[6] = fmaf(ws, xc.z, acc[6]);
                acc[7] = fmaf(ws, xc.w, acc[7]);
            }
        }
        // restage [i][co] (lanes co consecutive -> conflict-free), then the
        // linear layout matches y (n,48) exactly -> pure float4 copy out
#pragma unroll
        for (int i2 = 0; i2 < 8; ++i2) yo[(q * 8 + i2) * GOUT + co] = acc[i2];
        __syncthreads();

        float* yg = y + ((size_t)(b * NG + g) * NN + n0) * GIN;
        for (int t = tid; t < NT1 * 12; t += TPB1)
            ((float4*)yg)[t] = ((const float4*)yo)[t];
        __syncthreads();
    }
}

// ---------------------------------------------------------------------------
// Kernel 2 (gather_y): out = ReLU((1+eps)*y_i + sum_j y_j + bias), plus the
// (n,48) -> (48,n) output transpose done via direct 64B-coalesced scalar
// stores.  NO weights, NO GEMM, NO per-group barriers: after idx staging the
// kernel is pure gather -> the whole register file backs in-flight loads.
//   1024 blocks of 64 nodes, b = blk&3 (proven L2 phase scheme).
//   Lane map: e = tid/16 (float4 slot, 0..11), isub = tid%16 (node).
//   Per load instruction a wave covers 16 slices x 64 B fully-used lines.
// ---------------------------------------------------------------------------
constexpr int NT2  = 64;
constexpr int TPB2 = 192;
constexpr int IST  = 20;   // idx_lds row stride (pad 16->20: 2-way banks, 16B-aligned)

__global__ __launch_bounds__(TPB2, 3) void gather_y(const float* __restrict__ y,
                                                    const int*   __restrict__ idx,
                                                    const float* __restrict__ bias,
                                                    const float* __restrict__ eps,
                                                    float* __restrict__ out) {
    __shared__ __align__(16) int idx_lds[NT2 * IST];   // 5 KB

    const int tid = threadIdx.x;
    const int blk = blockIdx.x;
    const int b   = blk & 3;
    const int n0  = (blk >> 2) * NT2;

    const float e1 = 1.0f + eps[0];

    {
        const int* gi = idx + ((size_t)b * NN + n0) * KK;
        for (int t = tid; t < NT2 * KK; t += TPB2)
            idx_lds[(t >> 4) * IST + (t & 15)] = gi[t];
    }

    const int e    = tid >> 4;   // 0..11: channels 4e..4e+3
    const int isub = tid & 15;   // 0..15

    float* ob = out + (size_t)b * COUT * NN;
    __syncthreads();

#pragma unroll
    for (int g = 0; g < NG; ++g) {
        const float4* yg4 = (const float4*)(y + (size_t)(b * NG + g) * NN * GIN);
        const float4  bv  = ((const float4*)(bias + g * GOUT))[e];
#pragma unroll
        for (int r = 0; r < 4; ++r) {
            const int i = isub + 16 * r;
            const int4* ip = (const int4*)(idx_lds + i * IST);
            const int4 ja = ip[0], jb = ip[1], jc = ip[2], jd = ip[3];
            // all 17 loads issued before any arithmetic; named temporaries
            // (no runtime-indexed arrays), sched_barrier keeps the batch intact
            const float4 s  = yg4[(n0 + i) * 12 + e];
            float4 v0  = yg4[ja.x * 12 + e];
            float4 v1  = yg4[ja.y * 12 + e];
            float4 v2  = yg4[ja.z * 12 + e];
            float4 v3  = yg4[ja.w * 12 + e];
            float4 v4  = yg4[jb.x * 12 + e];
            float4 v5  = yg4[jb.y * 12 + e];
            float4 v6  = yg4[jb.z * 12 + e];
            float4 v7  = yg4[jb.w * 12 + e];
            float4 v8  = yg4[jc.x * 12 + e];
            float4 v9  = yg4[jc.y * 12 + e];
            float4 v10 = yg4[jc.z * 12 + e];
            float4 v11 = yg4[jc.w * 12 + e];
            float4 v12 = yg4[jd.x * 12 + e];
            float4 v13 = yg4[jd.y * 12 + e];
            float4 v14 = yg4[jd.z * 12 + e];
            float4 v15 = yg4[jd.w * 12 + e];
            __builtin_amdgcn_sched_barrier(0);
            // pairwise tree (short dependence chains)
            const float4 a0 = f4add(v0,  v1),  a1 = f4add(v2,  v3);
            const float4 a2 = f4add(v4,  v5),  a3 = f4add(v6,  v7);
            const float4 a4 = f4add(v8,  v9),  a5 = f4add(v10, v11);
            const float4 a6 = f4add(v12, v13), a7 = f4add(v14, v15);
            const float4 b0 = f4add(a0, a1), b1 = f4add(a2, a3);
            const float4 b2 = f4add(a4, a5), b3 = f4add(a6, a7);
            const float4 c0 = f4add(b0, b1), c1 = f4add(b2, b3);
            const float4 t  = f4add(c0, c1);
            float4 rr;
            rr.x = fmaxf(fmaf(e1, s.x, t.x + bv.x), 0.0f);
            rr.y = fmaxf(fmaf(e1, s.y, t.y + bv.y), 0.0f);
            rr.z = fmaxf(fmaf(e1, s.z, t.z + bv.z), 0.0f);
            rr.w = fmaxf(fmaf(e1, s.w, t.w + bv.w), 0.0f);
            // direct transpose-store: per component, 16 consecutive lanes
            // write 16 consecutive floats -> full 64B lines, no LDS restage
            float* orow = ob + (size_t)(g * GOUT + 4 * e) * NN + (n0 + i);
            orow[0]              = rr.x;
            orow[(size_t)NN]     = rr.y;
            orow[(size_t)2 * NN] = rr.z;
            orow[(size_t)3 * NN] = rr.w;
        }
    }
}

// ---------------------------------------------------------------------------
extern "C" void kernel_launch(void* const* d_in, const int* in_sizes, int n_in,
                              void* d_out, int out_size, void* d_ws, size_t ws_size,
                              hipStream_t stream) {
    const float* x      = (const float*)d_in[0];
    const int*   edge   = (const int*)  d_in[1];  // edge_index[0] = first half
    const float* weight = (const float*)d_in[2];
    const float* bias   = (const float*)d_in[3];
    const float* eps    = (const float*)d_in[4];
    float*       out    = (float*)d_out;
    float*       y      = (float*)d_ws;           // B*N*192 floats = 50.3 MB

    gemm_y<<<B * (NN / NT1), TPB1, 0, stream>>>(x, weight, y);
    gather_y<<<B * (NN / NT2), TPB2, 0, stream>>>(y, edge, bias, eps, out);
}

// Round 5
// 78.201 us; speedup vs baseline: 1.6952x; 1.6952x over previous
//
#include <hip/hip_runtime.h>
#include <hip/hip_fp16.h>

constexpr int B    = 4;
constexpr int CIN  = 192;
constexpr int COUT = 192;
constexpr int NN   = 16384;
constexpr int KK   = 16;
constexpr int NG   = 4;    // groups
constexpr int GIN  = 48;   // fan_in per group
constexpr int GOUT = 48;   // out channels per group
constexpr int NT   = 64;   // nodes per block: 1024 blocks = 4/CU (proven geometry)
constexpr int TPB  = 192;
constexpr int IST  = 20;   // idx_lds row stride (pad 16->20, 16B-aligned, bank-spread)
constexpr int HST  = 52;   // h_lds row stride  (pad 48->52, 16B-aligned, bank-spread)

// ---------------------------------------------------------------------------
// Kernel 1: transpose + fp16 convert: x (B,C,N) f32 -> xh (b,g,n,48) f16.
// Each node's group-slice is 96 B contiguous; per-(b,g) slice = 1.6 MB
// (comfortably L2-resident per XCD).  fp16 HALVES the gather's
// lane-address count — the measured wall (R0/R2/R4 all ~88-95 us at
// 5.35e7 divergent lane-addresses = 1/cy/CU).
// ---------------------------------------------------------------------------
__global__ __launch_bounds__(256) void transpose_h(const float* __restrict__ x,
                                                   __half* __restrict__ xh) {
    __shared__ float tile[32][33];
    const int b  = blockIdx.z;
    const int n0 = blockIdx.x * 32;
    const int c0 = blockIdx.y * 32;
    const int tx = threadIdx.x;  // 0..31
    const int ty = threadIdx.y;  // 0..7
    const float* xb  = x  + (size_t)b * CIN * NN;
    __half*      xhb = xh + (size_t)b * NN * CIN;
#pragma unroll
    for (int i = 0; i < 32; i += 8)
        tile[ty + i][tx] = xb[(size_t)(c0 + ty + i) * NN + (n0 + tx)];
    __syncthreads();
#pragma unroll
    for (int i = 0; i < 32; i += 8) {
        const int c = c0 + tx, n = n0 + ty + i;
        // consecutive tx -> consecutive halfs (within 48-ch group runs)
        xhb[((size_t)(c / GIN) * NN + n) * GIN + (c % GIN)] =
            __float2half(tile[tx][ty + i]);
    }
}

__device__ __forceinline__ void cvt8(uint4 u, float4& lo, float4& hi) {
    const __half2* h = (const __half2*)&u;
    const float2 f0 = __half22float2(h[0]), f1 = __half22float2(h[1]);
    const float2 f2 = __half22float2(h[2]), f3 = __half22float2(h[3]);
    lo = make_float4(f0.x, f0.y, f1.x, f1.y);
    hi = make_float4(f2.x, f2.y, f3.x, f3.y);
}
__device__ __forceinline__ void acc8(float4& lo, float4& hi, uint4 u) {
    float4 l, h; cvt8(u, l, h);
    lo.x += l.x; lo.y += l.y; lo.z += l.z; lo.w += l.w;
    hi.x += h.x; hi.y += h.y; hi.z += h.z; hi.w += h.w;
}

// ---------------------------------------------------------------------------
// Kernel 2 (fused): per group: fp16 gather+sum (fp32 accum) -> h_lds ->
// grouped GEMM (fp32 weights) -> ReLU -> direct 64B-per-thread stores.
//   - lockstep phases + b=blk&3: gather working set L2-resident (R0-proven,
//     FETCH = compulsory only).
//   - weights loaded AFTER the gather barrier behind sched_barrier(0):
//     never pinned during the gather (R0-R3 lesson).
//   - no o_lds: thread (co,q) owns out[g*48+co][n0+q*16..+15] = one 64 B
//     line, written as 4 float4 -> L2 write-combines to full sectors.
// ---------------------------------------------------------------------------
__global__ __launch_bounds__(TPB, 3) void gin_fused(const __half* __restrict__ xh,
                                                    const int*   __restrict__ idx,
                                                    const float* __restrict__ w,
                                                    const float* __restrict__ bias,
                                                    const float* __restrict__ eps,
                                                    float* __restrict__ out) {
    __shared__ __align__(16) float h_lds[NT * HST];   // 13.3 KB
    __shared__ __align__(16) int   idx_lds[NT * IST]; // 5.1 KB

    const int tid = threadIdx.x;
    const int blk = blockIdx.x;
    const int b   = blk & 3;
    const int n0  = (blk >> 2) * NT;

    const float e1 = 1.0f + eps[0];

    {
        const int* gi = idx + ((size_t)b * NN + n0) * KK;
        for (int t = tid; t < NT * KK; t += TPB)
            idx_lds[(t >> 4) * IST + (t & 15)] = gi[t];
    }

    // gather map: 6 lanes x uint4 (8 fp16 ch) cover one 96 B node-slice
    const int e    = tid % 6;    // 0..5
    const int isub = tid / 6;    // 0..31
    // gemm map
    const int co   = tid % GOUT; // 0..47
    const int q    = tid / GOUT; // 0..3

    const __half* xb = xh + (size_t)b * NN * CIN;
    float*        ob = out + (size_t)b * COUT * NN;

    __syncthreads();

    for (int g = 0; g < NG; ++g) {
        // ---- Phase 1: fp16 gather + fp32 sum ----
        const uint4* xg = (const uint4*)(xb + (size_t)g * NN * GIN);
#pragma unroll
        for (int r = 0; r < 2; ++r) {
            const int i = isub + 32 * r;
            const int4* ip = (const int4*)(idx_lds + i * IST);
            const int4 ja = ip[0], jb = ip[1], jc = ip[2], jd = ip[3];
            const uint4 us  = xg[(n0 + i) * 6 + e];
            const uint4 u0  = xg[ja.x * 6 + e], u1  = xg[ja.y * 6 + e];
            const uint4 u2  = xg[ja.z * 6 + e], u3  = xg[ja.w * 6 + e];
            const uint4 u4  = xg[jb.x * 6 + e], u5  = xg[jb.y * 6 + e];
            const uint4 u6  = xg[jb.z * 6 + e], u7  = xg[jb.w * 6 + e];
            const uint4 u8  = xg[jc.x * 6 + e], u9  = xg[jc.y * 6 + e];
            const uint4 u10 = xg[jc.z * 6 + e], u11 = xg[jc.w * 6 + e];
            const uint4 u12 = xg[jd.x * 6 + e], u13 = xg[jd.y * 6 + e];
            const uint4 u14 = xg[jd.z * 6 + e], u15 = xg[jd.w * 6 + e];
            // two independent accumulation chains (even/odd neighbors)
            float4 aLo, aHi, bLo, bHi;
            cvt8(u0, aLo, aHi);      cvt8(u1, bLo, bHi);
            acc8(aLo, aHi, u2);      acc8(bLo, bHi, u3);
            acc8(aLo, aHi, u4);      acc8(bLo, bHi, u5);
            acc8(aLo, aHi, u6);      acc8(bLo, bHi, u7);
            acc8(aLo, aHi, u8);      acc8(bLo, bHi, u9);
            acc8(aLo, aHi, u10);     acc8(bLo, bHi, u11);
            acc8(aLo, aHi, u12);     acc8(bLo, bHi, u13);
            acc8(aLo, aHi, u14);     acc8(bLo, bHi, u15);
            float4 sLo, sHi; cvt8(us, sLo, sHi);
            float4 lo, hi;
            lo.x = fmaf(e1, sLo.x, aLo.x + bLo.x);
            lo.y = fmaf(e1, sLo.y, aLo.y + bLo.y);
            lo.z = fmaf(e1, sLo.z, aLo.z + bLo.z);
            lo.w = fmaf(e1, sLo.w, aLo.w + bLo.w);
            hi.x = fmaf(e1, sHi.x, aHi.x + bHi.x);
            hi.y = fmaf(e1, sHi.y, aHi.y + bHi.y);
            hi.z = fmaf(e1, sHi.z, aHi.z + bHi.z);
            hi.w = fmaf(e1, sHi.w, aHi.w + bHi.w);
            float4* hp = (float4*)(h_lds + i * HST + e * 8);
            hp[0] = lo;
            hp[1] = hi;
        }
        __syncthreads();
        __builtin_amdgcn_sched_barrier(0);   // keep wv loads OUT of the gather

        // ---- Phase 2: grouped GEMM + ReLU + direct store ----
        float4 wv[12];
        {
            const float* wr = w + (size_t)(g * GOUT + co) * GIN;
#pragma unroll
            for (int ii = 0; ii < 12; ++ii) wv[ii] = ((const float4*)wr)[ii];
        }
        const float bi = bias[g * GOUT + co];
        float* orow = ob + (size_t)(g * GOUT + co) * NN + n0 + q * 16;
#pragma unroll
        for (int i4 = 0; i4 < 4; ++i4) {
            float av[4];
#pragma unroll
            for (int t = 0; t < 4; ++t) {
                const float* hr = h_lds + (q * 16 + i4 * 4 + t) * HST;
                float s = bi;
#pragma unroll
                for (int ii = 0; ii < 12; ++ii) {
                    const float4 hv = ((const float4*)hr)[ii];
                    s = fmaf(wv[ii].x, hv.x, s);
                    s = fmaf(wv[ii].y, hv.y, s);
                    s = fmaf(wv[ii].z, hv.z, s);
                    s = fmaf(wv[ii].w, hv.w, s);
                }
                av[t] = fmaxf(s, 0.0f);
            }
            ((float4*)orow)[i4] = make_float4(av[0], av[1], av[2], av[3]);
        }
        __syncthreads();   // h_lds safe to overwrite next group
    }
}

// ---------------------------------------------------------------------------
extern "C" void kernel_launch(void* const* d_in, const int* in_sizes, int n_in,
                              void* d_out, int out_size, void* d_ws, size_t ws_size,
                              hipStream_t stream) {
    const float* x      = (const float*)d_in[0];
    const int*   edge   = (const int*)  d_in[1];  // edge_index[0] = first half
    const float* weight = (const float*)d_in[2];
    const float* bias   = (const float*)d_in[3];
    const float* eps    = (const float*)d_in[4];
    float*       out    = (float*)d_out;
    __half*      xh     = (__half*)d_ws;          // B*N*192 halfs = 25.2 MB

    dim3 tblk(32, 8);
    dim3 tgrd(NN / 32, CIN / 32, B);
    transpose_h<<<tgrd, tblk, 0, stream>>>(x, xh);

    gin_fused<<<B * (NN / NT), TPB, 0, stream>>>(xh, edge, weight, bias, eps, out);
}